// Round 6
// baseline (150.719 us; speedup 1.0000x reference)
//
#include <hip/hip_runtime.h>
#include <hip/hip_bf16.h>
#include <cstdint>

#define NN    1024
#define FF    64
#define OUTF  128
#define KCAT  192
#define EPSV  1e-6f

typedef __attribute__((ext_vector_type(4))) float  f32x4;
typedef __attribute__((ext_vector_type(8))) __bf16 bf16x8;
typedef __attribute__((ext_vector_type(4))) __bf16 bf16x4;

#define MFMA16(a, b, c) __builtin_amdgcn_mfma_f32_16x16x32_bf16(a, b, c, 0, 0, 0)
#define GLOAD_LDS16(g, l)                                          \
    __builtin_amdgcn_global_load_lds(                              \
        (const __attribute__((address_space(1))) void*)(g),        \
        (__attribute__((address_space(3))) void*)(l), 16, 0, 0)

// ---------------------------------------------------------------------------
// Kernel 1: degree + diag-zero + f32->bf16 conversion of A, fused.
// BW-bound: 64MB read + 32MB write ~ 16us.
// ---------------------------------------------------------------------------
__global__ __launch_bounds__(256) void k_deg_cvt(const float* __restrict__ A,
                                                 float* __restrict__ d1,
                                                 float* __restrict__ sArr,
                                                 __bf16* __restrict__ Az) {
    int wave = threadIdx.x >> 6;
    int lane = threadIdx.x & 63;
    int row  = blockIdx.x * 4 + wave;          // [0, 16384)
    int i    = row & (NN - 1);                 // diag index within batch row
    const f32x4* rp = (const f32x4*)(A + (size_t)row * NN);
    __bf16* op = Az + (size_t)row * NN;
    float sum = 0.f;
#pragma unroll
    for (int t = 0; t < 4; ++t) {
        f32x4 v = rp[t * 64 + lane];
        int base = (t * 64 + lane) * 4;
#pragma unroll
        for (int q = 0; q < 4; ++q)
            if (base + q == i) v[q] = 0.f;     // zero diagonal
        sum += v[0] + v[1] + v[2] + v[3];
        bf16x4 o;
#pragma unroll
        for (int q = 0; q < 4; ++q) o[q] = (__bf16)v[q];
        *(bf16x4*)(op + base) = o;
    }
#pragma unroll
    for (int off = 32; off; off >>= 1) sum += __shfl_xor(sum, off);
    if (lane == 0) {
        float deg = 1.0f + sum;
        d1[row]   = 1.0f / (EPSV + deg);
        sArr[row] = 1.0f / (EPSV + sqrtf(deg));
    }
}

// ---------------------------------------------------------------------------
// Kernel 2: K-major bf16 copies of x and s*x, plus transposed bf16 kernel.
// ---------------------------------------------------------------------------
__global__ __launch_bounds__(256) void k_prep(const float* __restrict__ x,
                                              const float* __restrict__ sArr,
                                              const float* __restrict__ kern,
                                              __bf16* __restrict__ xT,
                                              __bf16* __restrict__ sxT,
                                              __bf16* __restrict__ KT) {
    __shared__ float tile[64][65];
    int bid = blockIdx.x;                  // 0..255
    int b   = bid >> 4;
    int k0  = (bid & 15) * 64;
    const float* xp = x + ((size_t)b * NN + k0) * FF;
    for (int i = threadIdx.x; i < 64 * 64; i += 256) {
        int r = i >> 6, c = i & 63;
        tile[r][c] = xp[r * FF + c];
    }
    __syncthreads();
    for (int i = threadIdx.x; i < 64 * 64; i += 256) {
        int c = i >> 6, kk = i & 63;
        float v  = tile[kk][c];
        float sv = v * sArr[b * NN + k0 + kk];
        size_t o = ((size_t)b * FF + c) * NN + k0 + kk;
        xT[o]  = (__bf16)v;
        sxT[o] = (__bf16)sv;
    }
    if (threadIdx.x < 96) {
        int idx = bid * 96 + threadIdx.x;
        int c = idx / KCAT;
        int k = idx - c * KCAT;
        KT[idx] = (__bf16)kern[k * OUTF + c];
    }
}

// ---------------------------------------------------------------------------
// Kernel 3: main fused kernel — max block-TLP, minimal barriers.
// Grid 1024 = 16 batches x 64 row-tiles (BM=16). 256 threads = 4 waves.
// LDS 32KB -> 4 blocks/CU; ALL 1024 blocks resident simultaneously.
//
// Stage: Az panel [16 rows x 1024 k] bf16 in MFMA-fragment layout via
// global_load_lds(16B) (pre-swizzled per-lane source, linear LDS dest):
//   chunk t (1KB): smem[t*1024 + l*16] = Az[row0+(l&15)][t*32+(l>>4)*8 ..+8]
// One __syncthreads, then a 32-step BARRIER-FREE loop: per step one
// conflict-free ds_read_b128 (all 4 waves same addr -> broadcast) + 2 global
// bf16x8 loads (xT,sxT; wave w4 owns features w4*16..+16) + 2 MFMA (P,Q).
// No barriers inside -> compiler pipelines loads across the whole run;
// cross-block TLP (4/CU) hides panel-stage latency.
//
// Epilogue: o1/o2/o3 -> bf16 os (overlaid on panel, stride 216 for <=2-way
// banks), swapped-operand GEMM vs KT -> bias+relu -> coalesced f32x4 stores.
// ---------------------------------------------------------------------------
__global__ __launch_bounds__(256, 4) void k_main(const __bf16* __restrict__ Az,
                                                 const float* __restrict__ x,
                                                 const float* __restrict__ bias,
                                                 const float* __restrict__ d1g,
                                                 const float* __restrict__ sg,
                                                 const __bf16* __restrict__ xT,
                                                 const __bf16* __restrict__ sxT,
                                                 const __bf16* __restrict__ KT,
                                                 float* __restrict__ out) {
    __shared__ __align__(16) char smem[32768];   // panel; os overlaid later

    const int tid  = threadIdx.x;
    const int w4   = tid >> 6;          // wave 0..3 = feature group
    const int lane = tid & 63;
    const int l15  = lane & 15;
    const int hi   = lane >> 4;         // 0..3
    const int h8   = hi * 8;

    // XCD-chunked swizzle: xcd = bid&7 gets contiguous work range (2 batches)
    const int idx  = (blockIdx.x & 7) * 128 + (blockIdx.x >> 3);
    const int b    = idx >> 6;
    const int row0 = (idx & 63) * 16;

    // ---- stage Az panel (wave w4 issues chunks t = c*4 + w4) ----
    {
        const __bf16* AzB = Az + (size_t)(b * NN + row0 + l15) * NN + h8;
#pragma unroll
        for (int c = 0; c < 8; ++c) {
            int t = c * 4 + w4;
            GLOAD_LDS16(AzB + t * 32, smem + t * 1024);
        }
    }

    const __bf16* xPb = xT  + ((size_t)(b * FF + w4 * 16 + l15)) * NN + h8;
    const __bf16* sPb = sxT + ((size_t)(b * FF + w4 * 16 + l15)) * NN + h8;
    const char* ldsA = smem + lane * 16;

    __syncthreads();    // full drain: panel complete, visible to all waves

    // ---- 32-step barrier-free K loop ----
    f32x4 P = {}, Q = {};
#pragma unroll
    for (int t = 0; t < 32; ++t) {
        bf16x8 a  = *(const bf16x8*)(ldsA + t * 1024);
        bf16x8 xf = *(const bf16x8*)(xPb + t * 32);
        bf16x8 sf = *(const bf16x8*)(sPb + t * 32);
        P = MFMA16(a, xf, P);
        Q = MFMA16(a, sf, Q);
    }

    __syncthreads();    // panel reads retired; safe to overlay os

    // ---- build o = [o1 | o2 | o3] in LDS (each wave owns its 16 features)
    __bf16 (*os)[216] = (__bf16(*)[216])smem;        // 16 x 216 x 2B = 6.9KB
#pragma unroll
    for (int j = 0; j < 4; ++j) {
        int rr   = hi * 4 + j;                        // local row
        int grow = b * NN + row0 + rr;
        float dv = d1g[grow];
        float sv = sg[grow];
        int cc   = w4 * 16 + l15;
        float xv = x[(size_t)grow * FF + cc];
        os[rr][cc]       = (__bf16)P[j];
        os[rr][64 + cc]  = (__bf16)(dv * (P[j] + xv));
        os[rr][128 + cc] = (__bf16)(sv * (Q[j] + sv * xv));
    }
    __syncthreads();

    // ---- epilogue GEMM (swapped operands): wave w4 -> out cols w4*32..+32
    f32x4 e0 = {}, e1 = {};
#pragma unroll
    for (int ks = 0; ks < 6; ++ks) {
        bf16x8 of = *(const bf16x8*)&os[l15][ks * 32 + h8];
        bf16x8 k0 = *(const bf16x8*)&KT[(size_t)(w4 * 32 + l15) * KCAT + ks * 32 + h8];
        bf16x8 k1 = *(const bf16x8*)&KT[(size_t)(w4 * 32 + 16 + l15) * KCAT + ks * 32 + h8];
        e0 = MFMA16(k0, of, e0);   // D rows = out cols, cols = os rows
        e1 = MFMA16(k1, of, e1);
    }
    {
        const size_t orow = (size_t)(b * NN + row0 + l15) * OUTF;
#pragma unroll
        for (int g = 0; g < 2; ++g) {
            f32x4 ev = g ? e1 : e0;
            int col0 = w4 * 32 + g * 16 + hi * 4;
            f32x4 bv = *(const f32x4*)&bias[col0];
            f32x4 rv;
#pragma unroll
            for (int j = 0; j < 4; ++j) {
                float v = ev[j] + bv[j];
                rv[j] = v > 0.f ? v : 0.f;
            }
            *(f32x4*)&out[orow + col0] = rv;
        }
    }
}

// ---------------------------------------------------------------------------
extern "C" void kernel_launch(void* const* d_in, const int* in_sizes, int n_in,
                              void* d_out, int out_size, void* d_ws, size_t ws_size,
                              hipStream_t stream) {
    const float* x    = (const float*)d_in[0];
    const float* A    = (const float*)d_in[1];
    const float* kern = (const float*)d_in[2];
    const float* bias = (const float*)d_in[3];
    float* out = (float*)d_out;

    char* ws = (char*)d_ws;
    __bf16* Az  = (__bf16*)(ws);                                   // 32 MB
    float*  d1  = (float*)(ws + 33554432);                         // 64 KB
    float*  s   = (float*)(ws + 33554432 + 65536);                 // 64 KB
    __bf16* xT  = (__bf16*)(ws + 33554432 + 131072);               // 2 MB
    __bf16* sxT = (__bf16*)(ws + 33554432 + 131072 + 2097152);     // 2 MB
    __bf16* KT  = (__bf16*)(ws + 33554432 + 131072 + 2 * 2097152); // 48 KB
    (void)ws_size; (void)in_sizes; (void)n_in; (void)out_size;

    k_deg_cvt<<<dim3(4096), dim3(256), 0, stream>>>(A, d1, s, Az);
    k_prep<<<dim3(256), dim3(256), 0, stream>>>(x, s, kern, xT, sxT, KT);
    k_main<<<dim3(1024), dim3(256), 0, stream>>>(Az, x, bias, d1, s, xT, sxT, KT, out);
}

// Round 7
// 136.776 us; speedup vs baseline: 1.1019x; 1.1019x over previous
//
#include <hip/hip_runtime.h>
#include <hip/hip_bf16.h>
#include <cstdint>

#define NN    1024
#define FF    64
#define OUTF  128
#define KCAT  192
#define EPSV  1e-6f

typedef __attribute__((ext_vector_type(4))) float  f32x4;
typedef __attribute__((ext_vector_type(8))) __bf16 bf16x8;
typedef __attribute__((ext_vector_type(4))) __bf16 bf16x4;

#define MFMA16(a, b, c) __builtin_amdgcn_mfma_f32_16x16x32_bf16(a, b, c, 0, 0, 0)
#define GLOAD_LDS16(g, l)                                          \
    __builtin_amdgcn_global_load_lds(                              \
        (const __attribute__((address_space(1))) void*)(g),        \
        (__attribute__((address_space(3))) void*)(l), 16, 0, 0)

// ---------------------------------------------------------------------------
// Kernel 1: degree + diag-zero + f32->bf16 conversion of A, fused.
// BW-bound: 64MB read + 32MB write ~ 15us.
// ---------------------------------------------------------------------------
__global__ __launch_bounds__(256) void k_deg_cvt(const float* __restrict__ A,
                                                 float* __restrict__ d1,
                                                 float* __restrict__ sArr,
                                                 __bf16* __restrict__ Az) {
    int wave = threadIdx.x >> 6;
    int lane = threadIdx.x & 63;
    int row  = blockIdx.x * 4 + wave;          // [0, 16384)
    int i    = row & (NN - 1);                 // diag index within batch row
    const f32x4* rp = (const f32x4*)(A + (size_t)row * NN);
    __bf16* op = Az + (size_t)row * NN;
    float sum = 0.f;
#pragma unroll
    for (int t = 0; t < 4; ++t) {
        f32x4 v = rp[t * 64 + lane];
        int base = (t * 64 + lane) * 4;
#pragma unroll
        for (int q = 0; q < 4; ++q)
            if (base + q == i) v[q] = 0.f;     // zero diagonal
        sum += v[0] + v[1] + v[2] + v[3];
        bf16x4 o;
#pragma unroll
        for (int q = 0; q < 4; ++q) o[q] = (__bf16)v[q];
        *(bf16x4*)(op + base) = o;
    }
#pragma unroll
    for (int off = 32; off; off >>= 1) sum += __shfl_xor(sum, off);
    if (lane == 0) {
        float deg = 1.0f + sum;
        d1[row]   = 1.0f / (EPSV + deg);
        sArr[row] = 1.0f / (EPSV + sqrtf(deg));
    }
}

// ---------------------------------------------------------------------------
// Kernel 2: K-major bf16 copies of x and s*x, plus transposed bf16 kernel.
// ---------------------------------------------------------------------------
__global__ __launch_bounds__(256) void k_prep(const float* __restrict__ x,
                                              const float* __restrict__ sArr,
                                              const float* __restrict__ kern,
                                              __bf16* __restrict__ xT,
                                              __bf16* __restrict__ sxT,
                                              __bf16* __restrict__ KT) {
    __shared__ float tile[64][65];
    int bid = blockIdx.x;                  // 0..255
    int b   = bid >> 4;
    int k0  = (bid & 15) * 64;
    const float* xp = x + ((size_t)b * NN + k0) * FF;
    for (int i = threadIdx.x; i < 64 * 64; i += 256) {
        int r = i >> 6, c = i & 63;
        tile[r][c] = xp[r * FF + c];
    }
    __syncthreads();
    for (int i = threadIdx.x; i < 64 * 64; i += 256) {
        int c = i >> 6, kk = i & 63;
        float v  = tile[kk][c];
        float sv = v * sArr[b * NN + k0 + kk];
        size_t o = ((size_t)b * FF + c) * NN + k0 + kk;
        xT[o]  = (__bf16)v;
        sxT[o] = (__bf16)sv;
    }
    if (threadIdx.x < 96) {
        int idx = bid * 96 + threadIdx.x;
        int c = idx / KCAT;
        int k = idx - c * KCAT;
        KT[idx] = (__bf16)kern[k * OUTF + c];
    }
}

// ---------------------------------------------------------------------------
// Kernel 3: main fused kernel — ALL operands DMA-staged, counted-vmcnt
// double-buffered pipeline; K-loop touches ONLY LDS (no VM ops -> the
// counted waits actually overlap, unlike R4).
//
// Grid 512 = 16 batches x 32 row-tiles (BM=32). 512 threads = 8 waves.
// LDS 2 x 40KB K-tile buffers (K-tile = 128 elems = 4 MFMA k-steps):
//   buf + [0,8K)    A chunks  (ks*2+rg)*1KB : Az[row0+rg*16+(l&15)][ks*32+(l>>4)*8..]
//   buf + [8K,24K)  x chunks  (ks*4+fg)*1KB : xT[fg*16+(l&15)][same k]
//   buf + [24K,40K) sx chunks (ks*4+fg)*1KB : sxT[...]
// Each wave stages exactly 5 chunks/tile (1 A + 2 x + 2 sx), issued in tile
// order -> in-order vmcnt retirement makes "wait vmcnt(5)" == "tile t ready,
// tile t+1 still streaming". Raw s_barrier (NOT __syncthreads: that drains
// vmcnt(0) and kills the pipeline).
// Compute wave (rg=w>>2, fg=w&3): per k-step 3 conflict-free ds_read_b128
// (lane*16 + imm) + 2 MFMA (P,Q). 8 tiles. Epilogue: o1/o2/o3 -> bf16 os
// (overlaid on buf0) -> swapped-operand GEMM vs KT -> bias+relu -> f32x4.
// ---------------------------------------------------------------------------
__global__ __launch_bounds__(512, 4) void k_main(const __bf16* __restrict__ Az,
                                                 const float* __restrict__ x,
                                                 const float* __restrict__ bias,
                                                 const float* __restrict__ d1g,
                                                 const float* __restrict__ sg,
                                                 const __bf16* __restrict__ xT,
                                                 const __bf16* __restrict__ sxT,
                                                 const __bf16* __restrict__ KT,
                                                 float* __restrict__ out) {
    __shared__ __align__(16) char smem[81920];   // 2 x 40KB; os overlays buf0

    const int tid  = threadIdx.x;
    const int w    = tid >> 6;          // wave 0..7
    const int lane = tid & 63;
    const int l15  = lane & 15;
    const int hi   = lane >> 4;         // 0..3
    const int h8   = hi * 8;

    // XCD-chunked swizzle: XCD x gets idx [x*64, x*64+64) = 2 batches.
    const int idx  = (blockIdx.x & 7) * 64 + (blockIdx.x >> 3);
    const int b    = idx >> 5;
    const int row0 = (idx & 31) * 32;

    // per-thread staging source pointers (fragment-order pre-swizzle)
    const __bf16* AzRow = Az  + (size_t)(b * NN + row0 + (w & 1) * 16 + l15) * NN
                              + (w >> 1) * 32 + h8;           // A chunk id = w
    const __bf16* xRow  = xT  + (size_t)(b * FF + (w & 3) * 16 + l15) * NN
                              + (w >> 2) * 32 + h8;           // x chunks w, w+8
    const __bf16* sxRow = sxT + (size_t)(b * FF + (w & 3) * 16 + l15) * NN
                              + (w >> 2) * 32 + h8;

#define STAGE(t, pb)                                                     \
    {                                                                    \
        char* bb = smem + (pb) * 40960;                                  \
        const int kofs = (t) * 128;                                      \
        GLOAD_LDS16(AzRow + kofs,      bb + w * 1024);                   \
        GLOAD_LDS16(xRow + kofs,       bb + 8192  + w * 1024);           \
        GLOAD_LDS16(xRow + kofs + 64,  bb + 8192  + (w + 8) * 1024);     \
        GLOAD_LDS16(sxRow + kofs,      bb + 24576 + w * 1024);           \
        GLOAD_LDS16(sxRow + kofs + 64, bb + 24576 + (w + 8) * 1024);     \
    }

    STAGE(0, 0)
    STAGE(1, 1)

    const int rg = w >> 2;     // compute row group
    const int fg = w & 3;      // compute feature group

    f32x4 P = {}, Q = {};
#pragma unroll
    for (int t = 0; t < 8; ++t) {
        if (t < 7) { asm volatile("s_waitcnt vmcnt(5)" ::: "memory"); }
        else       { asm volatile("s_waitcnt vmcnt(0)" ::: "memory"); }
        __builtin_amdgcn_s_barrier();            // all waves' tile-t chunks in
        {
            const char* bb = smem + (t & 1) * 40960;
#pragma unroll
            for (int ks = 0; ks < 4; ++ks) {
                bf16x8 a  = *(const bf16x8*)(bb + (ks * 2 + rg) * 1024 + lane * 16);
                bf16x8 xf = *(const bf16x8*)(bb + 8192  + (ks * 4 + fg) * 1024 + lane * 16);
                bf16x8 sf = *(const bf16x8*)(bb + 24576 + (ks * 4 + fg) * 1024 + lane * 16);
                P = MFMA16(a, xf, P);
                Q = MFMA16(a, sf, Q);
            }
        }
        __builtin_amdgcn_s_barrier();            // buf[t&1] free to overwrite
        if (t < 6) STAGE(t + 2, t & 1)
    }
#undef STAGE

    // ---- build o = [o1 | o2 | o3] in LDS (overlay buf0) -------------------
    __bf16 (*os)[216] = (__bf16(*)[216])smem;    // 32 x 216 x 2B = 13.5KB
#pragma unroll
    for (int j = 0; j < 4; ++j) {
        int rr   = rg * 16 + hi * 4 + j;
        int grow = b * NN + row0 + rr;
        float dv = d1g[grow];
        float sv = sg[grow];
        int cc   = fg * 16 + l15;
        float xv = x[(size_t)grow * FF + cc];
        os[rr][cc]       = (__bf16)P[j];
        os[rr][64 + cc]  = (__bf16)(dv * (P[j] + xv));
        os[rr][128 + cc] = (__bf16)(sv * (Q[j] + sv * xv));
    }
    __syncthreads();

    // ---- epilogue GEMM (swapped operands): out[32x128] --------------------
    const int rge = w >> 2;         // row half
    const int cge = w & 3;          // col group of 32
    f32x4 e0 = {}, e1 = {};
#pragma unroll
    for (int ks = 0; ks < 6; ++ks) {
        bf16x8 of = *(const bf16x8*)&os[rge * 16 + l15][ks * 32 + h8];
        bf16x8 k0 = *(const bf16x8*)&KT[(size_t)(cge * 32 + l15) * KCAT + ks * 32 + h8];
        bf16x8 k1 = *(const bf16x8*)&KT[(size_t)(cge * 32 + 16 + l15) * KCAT + ks * 32 + h8];
        e0 = MFMA16(k0, of, e0);    // D rows = out cols, D cols = os rows
        e1 = MFMA16(k1, of, e1);
    }
    {
        const size_t orow = (size_t)(b * NN + row0 + rge * 16 + l15) * OUTF;
#pragma unroll
        for (int g = 0; g < 2; ++g) {
            f32x4 ev = g ? e1 : e0;
            int col0 = cge * 32 + g * 16 + hi * 4;
            f32x4 bv = *(const f32x4*)&bias[col0];
            f32x4 rv;
#pragma unroll
            for (int j = 0; j < 4; ++j) {
                float v = ev[j] + bv[j];
                rv[j] = v > 0.f ? v : 0.f;
            }
            *(f32x4*)&out[orow + col0] = rv;
        }
    }
}

// ---------------------------------------------------------------------------
extern "C" void kernel_launch(void* const* d_in, const int* in_sizes, int n_in,
                              void* d_out, int out_size, void* d_ws, size_t ws_size,
                              hipStream_t stream) {
    const float* x    = (const float*)d_in[0];
    const float* A    = (const float*)d_in[1];
    const float* kern = (const float*)d_in[2];
    const float* bias = (const float*)d_in[3];
    float* out = (float*)d_out;

    char* ws = (char*)d_ws;
    __bf16* Az  = (__bf16*)(ws);                                   // 32 MB
    float*  d1  = (float*)(ws + 33554432);                         // 64 KB
    float*  s   = (float*)(ws + 33554432 + 65536);                 // 64 KB
    __bf16* xT  = (__bf16*)(ws + 33554432 + 131072);               // 2 MB
    __bf16* sxT = (__bf16*)(ws + 33554432 + 131072 + 2097152);     // 2 MB
    __bf16* KT  = (__bf16*)(ws + 33554432 + 131072 + 2 * 2097152); // 48 KB
    (void)ws_size; (void)in_sizes; (void)n_in; (void)out_size;

    k_deg_cvt<<<dim3(4096), dim3(256), 0, stream>>>(A, d1, s, Az);
    k_prep<<<dim3(256), dim3(256), 0, stream>>>(x, s, kern, xT, sxT, KT);
    k_main<<<dim3(512), dim3(512), 0, stream>>>(Az, x, bias, d1, s, xT, sxT, KT, out);
}

// Round 8
// 127.008 us; speedup vs baseline: 1.1867x; 1.0769x over previous
//
#include <hip/hip_runtime.h>
#include <hip/hip_bf16.h>
#include <cstdint>

#define NN    1024
#define FF    64
#define OUTF  128
#define KCAT  192
#define EPSV  1e-6f

typedef __attribute__((ext_vector_type(4))) float  f32x4;
typedef __attribute__((ext_vector_type(8))) __bf16 bf16x8;
typedef __attribute__((ext_vector_type(4))) __bf16 bf16x4;

#define MFMA16(a, b, c) __builtin_amdgcn_mfma_f32_16x16x32_bf16(a, b, c, 0, 0, 0)
#define GLOAD_LDS16(g, l)                                          \
    __builtin_amdgcn_global_load_lds(                              \
        (const __attribute__((address_space(1))) void*)(g),        \
        (__attribute__((address_space(3))) void*)(l), 16, 0, 0)

// ---------------------------------------------------------------------------
// Kernel 1: degree + diag-zero + f32->bf16 conversion of A, fused.
// BW-bound: 64MB read + 32MB write ~ 15us.
// ---------------------------------------------------------------------------
__global__ __launch_bounds__(256) void k_deg_cvt(const float* __restrict__ A,
                                                 float* __restrict__ d1,
                                                 float* __restrict__ sArr,
                                                 __bf16* __restrict__ Az) {
    int wave = threadIdx.x >> 6;
    int lane = threadIdx.x & 63;
    int row  = blockIdx.x * 4 + wave;          // [0, 16384)
    int i    = row & (NN - 1);                 // diag index within batch row
    const f32x4* rp = (const f32x4*)(A + (size_t)row * NN);
    __bf16* op = Az + (size_t)row * NN;
    float sum = 0.f;
#pragma unroll
    for (int t = 0; t < 4; ++t) {
        f32x4 v = rp[t * 64 + lane];
        int base = (t * 64 + lane) * 4;
#pragma unroll
        for (int q = 0; q < 4; ++q)
            if (base + q == i) v[q] = 0.f;     // zero diagonal
        sum += v[0] + v[1] + v[2] + v[3];
        bf16x4 o;
#pragma unroll
        for (int q = 0; q < 4; ++q) o[q] = (__bf16)v[q];
        *(bf16x4*)(op + base) = o;
    }
#pragma unroll
    for (int off = 32; off; off >>= 1) sum += __shfl_xor(sum, off);
    if (lane == 0) {
        float deg = 1.0f + sum;
        d1[row]   = 1.0f / (EPSV + deg);
        sArr[row] = 1.0f / (EPSV + sqrtf(deg));
    }
}

// ---------------------------------------------------------------------------
// Kernel 2: K-major bf16 copies of x and s*x, plus transposed bf16 kernel.
// ---------------------------------------------------------------------------
__global__ __launch_bounds__(256) void k_prep(const float* __restrict__ x,
                                              const float* __restrict__ sArr,
                                              const float* __restrict__ kern,
                                              __bf16* __restrict__ xT,
                                              __bf16* __restrict__ sxT,
                                              __bf16* __restrict__ KT) {
    __shared__ float tile[64][65];
    int bid = blockIdx.x;                  // 0..255
    int b   = bid >> 4;
    int k0  = (bid & 15) * 64;
    const float* xp = x + ((size_t)b * NN + k0) * FF;
    for (int i = threadIdx.x; i < 64 * 64; i += 256) {
        int r = i >> 6, c = i & 63;
        tile[r][c] = xp[r * FF + c];
    }
    __syncthreads();
    for (int i = threadIdx.x; i < 64 * 64; i += 256) {
        int c = i >> 6, kk = i & 63;
        float v  = tile[kk][c];
        float sv = v * sArr[b * NN + k0 + kk];
        size_t o = ((size_t)b * FF + c) * NN + k0 + kk;
        xT[o]  = (__bf16)v;
        sxT[o] = (__bf16)sv;
    }
    if (threadIdx.x < 96) {
        int idx = bid * 96 + threadIdx.x;
        int c = idx / KCAT;
        int k = idx - c * KCAT;
        KT[idx] = (__bf16)kern[k * OUTF + c];
    }
}

// ---------------------------------------------------------------------------
// Kernel 3: main fused kernel — counted-vmcnt double-buffered DMA pipeline,
// ROW-MAJOR LDS tiles with XOR 16B-slot swizzle (both-sides): DMA source
// permutes slots WITHIN a 256B row (footprint contiguous -> dense 256B
// transactions, 4 rows per instruction), compute reads apply the same XOR
// -> 2-way max bank alias (free). Fixes R7's 16-way-scattered 64B DMA.
//
// Grid 512 = 16 batches x 32 row-tiles (BM=32). 512 threads = 8 waves.
// LDS 2 x 40KB K-tile buffers (K-tile = 128):
//   buf+[0,8K)    A  [32 rows][256B]   (row r = row0+r)
//   buf+[8K,24K)  x  [64 feat][256B]
//   buf+[24K,40K) sx [64 feat][256B]
// Swizzle: 16B-slot s of row r holds global slot s ^ (r&7).
// Wave w stages: A chunk w (rows 4w..4w+3), x chunks w,w+8, sx chunks w,w+8
// = 5 DMA/tile/wave -> steady-state wait vmcnt(5) = "tile t ready".
// Compute (rg=w>>2, fg=w&3): 12 ds_read_b128 + 8 MFMA per tile, LDS-only.
// Epilogue: o1/o2/o3 -> bf16 os -> swapped-operand GEMM vs KT -> f32x4 out.
// ---------------------------------------------------------------------------
__global__ __launch_bounds__(512, 4) void k_main(const __bf16* __restrict__ Az,
                                                 const float* __restrict__ x,
                                                 const float* __restrict__ bias,
                                                 const float* __restrict__ d1g,
                                                 const float* __restrict__ sg,
                                                 const __bf16* __restrict__ xT,
                                                 const __bf16* __restrict__ sxT,
                                                 const __bf16* __restrict__ KT,
                                                 float* __restrict__ out) {
    __shared__ __align__(16) char smem[81920];   // 2 x 40KB; os overlays buf0

    const int tid  = threadIdx.x;
    const int w    = tid >> 6;          // wave 0..7
    const int lane = tid & 63;
    const int l15  = lane & 15;
    const int hi   = lane >> 4;         // 0..3
    const int h8   = hi * 8;

    // XCD-chunked swizzle: XCD x gets idx [x*64, x*64+64) = 2 batches.
    const int idx  = (blockIdx.x & 7) * 64 + (blockIdx.x >> 3);
    const int b    = idx >> 5;
    const int row0 = (idx & 31) * 32;

    // ---- staging sources: 4 consecutive rows per chunk, slots XOR'd within
    // the row (contiguous 256B footprint -> dense transactions).
    const int rA = 4 * w + hi;                     // A tile row for this lane
    const int sA = (l15 ^ (rA & 7)) * 8;           // element offset in row
    const __bf16* Asrc = Az + (size_t)(b * NN + row0 + rA) * NN + sA;

    const int f0 = 4 * w + hi;                     // x/sx row, chunk w
    const int s0 = (l15 ^ (f0 & 7)) * 8;
    const int f1 = 32 + 4 * w + hi;                // x/sx row, chunk w+8
    const int s1 = (l15 ^ (f1 & 7)) * 8;
    const __bf16* Xsrc0 = xT  + (size_t)(b * FF + f0) * NN + s0;
    const __bf16* Xsrc1 = xT  + (size_t)(b * FF + f1) * NN + s1;
    const __bf16* Ssrc0 = sxT + (size_t)(b * FF + f0) * NN + s0;
    const __bf16* Ssrc1 = sxT + (size_t)(b * FF + f1) * NN + s1;

#define STAGE(t, pb)                                                     \
    {                                                                    \
        char* bb = smem + (pb) * 40960;                                  \
        const int ko = (t) * 128;                                        \
        GLOAD_LDS16(Asrc + ko,  bb + w * 1024);                          \
        GLOAD_LDS16(Xsrc0 + ko, bb + 8192  + w * 1024);                  \
        GLOAD_LDS16(Xsrc1 + ko, bb + 8192  + (w + 8) * 1024);            \
        GLOAD_LDS16(Ssrc0 + ko, bb + 24576 + w * 1024);                  \
        GLOAD_LDS16(Ssrc1 + ko, bb + 24576 + (w + 8) * 1024);            \
    }

    STAGE(0, 0)
    STAGE(1, 1)

    const int rg = w >> 2;     // compute row group
    const int fg = w & 3;      // compute feature group

    // compute-time LDS byte offsets (row-major + XOR slot swizzle)
    const int arow = rg * 16 + l15;                // A row 0..31
    const int frow = fg * 16 + l15;                // x/sx row 0..63
    const int swz  = (l15 & 7) << 4;               // same as (row&7)<<4
    const int aBase = arow * 256;
    const int xBase = 8192 + frow * 256;
    const int sBase = 24576 + frow * 256;

    f32x4 P = {}, Q = {};
#pragma unroll
    for (int t = 0; t < 8; ++t) {
        if (t < 7) { asm volatile("s_waitcnt vmcnt(5)" ::: "memory"); }
        else       { asm volatile("s_waitcnt vmcnt(0)" ::: "memory"); }
        __builtin_amdgcn_s_barrier();            // all waves' tile-t chunks in
        __builtin_amdgcn_sched_barrier(0);       // no hoisting across barrier
        {
            const char* bb = smem + (t & 1) * 40960;
#pragma unroll
            for (int ks = 0; ks < 4; ++ks) {
                const int ko = (ks * 64 + hi * 16) ^ swz;
                bf16x8 a  = *(const bf16x8*)(bb + aBase + ko);
                bf16x8 xf = *(const bf16x8*)(bb + xBase + ko);
                bf16x8 sf = *(const bf16x8*)(bb + sBase + ko);
                P = MFMA16(a, xf, P);
                Q = MFMA16(a, sf, Q);
            }
        }
        asm volatile("s_waitcnt lgkmcnt(0)" ::: "memory");
        __builtin_amdgcn_sched_barrier(0);
        __builtin_amdgcn_s_barrier();            // buf[t&1] free to overwrite
        if (t < 6) STAGE(t + 2, t & 1)
    }
#undef STAGE

    // ---- build o = [o1 | o2 | o3] in LDS (overlay buf0) -------------------
    __bf16 (*os)[216] = (__bf16(*)[216])smem;    // 32 x 216 x 2B = 13.5KB
#pragma unroll
    for (int j = 0; j < 4; ++j) {
        int rr   = rg * 16 + hi * 4 + j;
        int grow = b * NN + row0 + rr;
        float dv = d1g[grow];
        float sv = sg[grow];
        int cc   = fg * 16 + l15;
        float xv = x[(size_t)grow * FF + cc];
        os[rr][cc]       = (__bf16)P[j];
        os[rr][64 + cc]  = (__bf16)(dv * (P[j] + xv));
        os[rr][128 + cc] = (__bf16)(sv * (Q[j] + sv * xv));
    }
    __syncthreads();

    // ---- epilogue GEMM (swapped operands): out[32x128] --------------------
    const int rge = w >> 2;         // row half
    const int cge = w & 3;          // col group of 32
    f32x4 e0 = {}, e1 = {};
#pragma unroll
    for (int ks = 0; ks < 6; ++ks) {
        bf16x8 of = *(const bf16x8*)&os[rge * 16 + l15][ks * 32 + h8];
        bf16x8 k0 = *(const bf16x8*)&KT[(size_t)(cge * 32 + l15) * KCAT + ks * 32 + h8];
        bf16x8 k1 = *(const bf16x8*)&KT[(size_t)(cge * 32 + 16 + l15) * KCAT + ks * 32 + h8];
        e0 = MFMA16(k0, of, e0);    // D rows = out cols, D cols = os rows
        e1 = MFMA16(k1, of, e1);
    }
    {
        const size_t orow = (size_t)(b * NN + row0 + rge * 16 + l15) * OUTF;
#pragma unroll
        for (int g = 0; g < 2; ++g) {
            f32x4 ev = g ? e1 : e0;
            int col0 = cge * 32 + g * 16 + hi * 4;
            f32x4 bv = *(const f32x4*)&bias[col0];
            f32x4 rv;
#pragma unroll
            for (int j = 0; j < 4; ++j) {
                float v = ev[j] + bv[j];
                rv[j] = v > 0.f ? v : 0.f;
            }
            *(f32x4*)&out[orow + col0] = rv;
        }
    }
}

// ---------------------------------------------------------------------------
extern "C" void kernel_launch(void* const* d_in, const int* in_sizes, int n_in,
                              void* d_out, int out_size, void* d_ws, size_t ws_size,
                              hipStream_t stream) {
    const float* x    = (const float*)d_in[0];
    const float* A    = (const float*)d_in[1];
    const float* kern = (const float*)d_in[2];
    const float* bias = (const float*)d_in[3];
    float* out = (float*)d_out;

    char* ws = (char*)d_ws;
    __bf16* Az  = (__bf16*)(ws);                                   // 32 MB
    float*  d1  = (float*)(ws + 33554432);                         // 64 KB
    float*  s   = (float*)(ws + 33554432 + 65536);                 // 64 KB
    __bf16* xT  = (__bf16*)(ws + 33554432 + 131072);               // 2 MB
    __bf16* sxT = (__bf16*)(ws + 33554432 + 131072 + 2097152);     // 2 MB
    __bf16* KT  = (__bf16*)(ws + 33554432 + 131072 + 2 * 2097152); // 48 KB
    (void)ws_size; (void)in_sizes; (void)n_in; (void)out_size;

    k_deg_cvt<<<dim3(4096), dim3(256), 0, stream>>>(A, d1, s, Az);
    k_prep<<<dim3(256), dim3(256), 0, stream>>>(x, s, kern, xT, sxT, KT);
    k_main<<<dim3(512), dim3(512), 0, stream>>>(Az, x, bias, d1, s, xT, sxT, KT, out);
}